// Round 3
// baseline (191.859 us; speedup 1.0000x reference)
//
#include <hip/hip_runtime.h>
#include <stdint.h>

#define OH 250
#define OW 250
#define NPTS (OH*OW)        // 62500
#define NSEG 4              // y batches only (x-side is mathematically dead; verified R2-R10)
#define D 147               // 3*7*7
#define CH 3
#define IMH 256
#define IMW 256
#define NITER 17            // ceil(log2(62500)) + 1, per reference
#define NBUCK 8192
#define CAP 128             // slots/bucket; central lambda ~24, P(>128) ~ 0
#define SIG0 12.124355652982141  // sqrt(147): projection stddev model (bucketing only)

typedef unsigned long long u64;
typedef unsigned int u32;

// workspace layout (bytes)
#define OFF_SREC  0UL          // u64[4*8192*128] = 33,554,432
#define OFF_A     33554432UL   // u32[4*62500]    = 1,000,000
#define OFF_CURS  34559136UL   // u32[4*8192]     = 131,072   (old wts slot retired)
#define OFF_BASES 34690208UL   // u32[4*8193]     = 131,088
#define OFF_SUMS  34821296UL   // u64[4]          = 32
#define OFF_TICK  34821328UL   // u32[2]          = 8  (tick[0]=scan ticket, tick[1]=loss)
#define OFF_OFLOW 34821336UL   // u32[1]          = 4
#define OFF_FLAGS 34821340UL   // u32[4]          = 16 (per-seg scan-done flags)
#define WS_NEED   34821356UL
#define ZERO_BYTES (WS_NEED - OFF_CURS)            // 262,220: curs..flags in one memset

__device__ __forceinline__ u64 packd(double f) {
  u64 u = (u64)__double_as_longlong(f);
  return (u & 0x8000000000000000ULL) ? ~u : (u | 0x8000000000000000ULL);
}

// bucket from the 47-bit-truncated transformed key (monotone with key order)
__device__ __forceinline__ int bucket_of(u64 rec) {
  u64 t = rec & ~0x1FFFFULL;
  u64 bits = (t & 0x8000000000000000ULL) ? (t & 0x7FFFFFFFFFFFFFFFULL) : ~t;
  double v = __longlong_as_double((long long)bits);
  double z = (v + 4.0 * SIG0) * ((double)NBUCK / (8.0 * SIG0));
  int b = (z <= 0.0) ? 0 : (int)z;
  if (b > NBUCK - 1) b = NBUCK - 1;
  return b;
}

// ---- conv (3x7x7, f64) + direct bucket scatter. R13: setup_kern deleted — every block
// recomputes the 147 weights (identical op sequence as the validated setup_kern ->
// bit-identical f64 in all blocks -> identical records downstream). Adds ~600 cy/block,
// removes one kernel node + boundary drain. ----
__global__ __launch_bounds__(256) void conv_kern(const float* __restrict__ y,
                                                 const float* __restrict__ rnd,
                                                 u64* __restrict__ srec,
                                                 u32* __restrict__ curs,
                                                 u32* __restrict__ oflow) {
  __shared__ float tile[CH][22][22];
  __shared__ double wlds[D];
  int b = blockIdx.z;
  int tid = threadIdx.y * 16 + threadIdx.x;
  int lane = tid & 63;
  {  // weights: rand/std ddof=1 (same arithmetic as retired setup_kern, all waves replicate)
    const float* rb = rnd + b * D;
    double v0 = (double)rb[lane];
    double v1 = (double)rb[lane + 64];
    double v2 = (lane + 128 < D) ? (double)rb[lane + 128] : 0.0;
    double sm = v0 + v1 + v2;
    #pragma unroll
    for (int o = 32; o > 0; o >>= 1) sm += __shfl_xor(sm, o, 64);
    double mean = sm / (double)D;
    double d0 = v0 - mean, d1 = v1 - mean;
    double d2 = (lane + 128 < D) ? (v2 - mean) : 0.0;
    double ss = d0 * d0 + d1 * d1 + d2 * d2;
    #pragma unroll
    for (int o = 32; o > 0; o >>= 1) ss += __shfl_xor(ss, o, 64);
    double stdv = sqrt(ss / (double)(D - 1));
    if (tid < 64) {
      wlds[lane] = v0 / stdv;
      wlds[lane + 64] = v1 / stdv;
      if (lane + 128 < D) wlds[lane + 128] = v2 / stdv;
    }
  }
  const float* in = y + (size_t)b * CH * IMH * IMW;
  int bi = blockIdx.y * 16, bj = blockIdx.x * 16;
  for (int c = 0; c < CH; ++c)
    for (int t = tid; t < 22 * 22; t += 256) {
      int rr = t / 22, cc = t - rr * 22;
      int r = bi + rr, col = bj + cc;
      float v = 0.f;
      if (r < IMH && col < IMW) v = in[((size_t)c * IMH + r) * IMW + col];
      tile[c][rr][cc] = v;
    }
  __syncthreads();                                 // covers wlds + tile
  int i = bi + threadIdx.y, j = bj + threadIdx.x;
  if (i < OH && j < OW) {
    double acc = 0.0;
    #pragma unroll
    for (int c = 0; c < CH; ++c) {
      double ac = 0.0;                             // per-channel partial: 3 short chains
      #pragma unroll
      for (int ph = 0; ph < 7; ++ph)
        #pragma unroll
        for (int pw = 0; pw < 7; ++pw)
          ac = fma((double)tile[c][threadIdx.y + ph][threadIdx.x + pw],
                   wlds[c * 49 + ph * 7 + pw], ac);
      acc += ac;
    }
    int n = i * OW + j;
    u64 rec = (packd(acc) & ~0x1FFFFULL) | (u64)(u32)n;
    int bk = b * NBUCK + bucket_of(rec);
    u32 pos = atomicAdd(&curs[bk], 1u);
    if (pos < CAP) srec[(size_t)bk * CAP + pos] = rec;
    else atomicOr(oflow, 1u);                      // exactness tripwire (never expected)
  }
}

// ---- R13: fused scan+bsort. 1024 blocks x 512 = 2048 thr/CU, ALL blocks co-resident.
// First 4 ARRIVING blocks (ticket, no dispatch-order assumption; winners are resident by
// construction and wait on nothing -> deadlock-free) block-scan one segment each, publish
// bases via agent atomics + release flag. All blocks overlap record-load + rank compute
// (needs only curs/srec), then acquire-spin on flag and write at bases offset. ----
__global__ __launch_bounds__(512) void bsortscan_kern(const u64* __restrict__ srec,
                                                      const u32* __restrict__ curs,
                                                      u32* __restrict__ bases,
                                                      u32* __restrict__ flags,
                                                      u32* __restrict__ tick,
                                                      u32* __restrict__ a,
                                                      u32* __restrict__ oflow) {
  __shared__ u64 buf[8][CAP];
  __shared__ u32 wsum[8];
  __shared__ u32 ticket_s;
  int tid = threadIdx.x;
  int wid = tid >> 6, lane = tid & 63;
  if (tid == 0) ticket_s = atomicAdd(&tick[0], 1u);
  __syncthreads();
  if (ticket_s < NSEG) {                           // scanner block: scan segment 'ticket'
    int sseg = (int)ticket_s;
    const u32* cs = curs + sseg * NBUCK;
    u32 c[16]; u32 run = 0;
    #pragma unroll
    for (int m = 0; m < 16; ++m) {
      u32 v = cs[tid * 16 + m];
      c[m] = v > CAP ? CAP : v;                    // clamp: OOB-safety only
      run += c[m];
    }
    u32 inc = run;                                 // wave-inclusive scan
    #pragma unroll
    for (int o = 1; o < 64; o <<= 1) {
      u32 v = __shfl_up(inc, o, 64);
      if (lane >= o) inc += v;
    }
    if (lane == 63) wsum[wid] = inc;
    __syncthreads();
    u32 woff = 0;
    for (int w2 = 0; w2 < wid; ++w2) woff += wsum[w2];
    u32 ex = woff + inc - run;                     // block-exclusive prefix
    u32* bs = bases + sseg * (NBUCK + 1);
    #pragma unroll
    for (int m = 0; m < 16; ++m) {
      __hip_atomic_store(&bs[tid * 16 + m], ex, __ATOMIC_RELAXED, __HIP_MEMORY_SCOPE_AGENT);
      ex += c[m];
    }
    if (tid == 511) {
      __hip_atomic_store(&bs[NBUCK], ex, __ATOMIC_RELAXED, __HIP_MEMORY_SCOPE_AGENT);
      if (ex != NPTS) atomicOr(oflow, 2u);         // loud tripwire
    }
    __syncthreads();                               // drains vmcnt -> all stores agent-visible
    if (tid == 0)
      __hip_atomic_store(&flags[sseg], 1u, __ATOMIC_RELEASE, __HIP_MEMORY_SCOPE_AGENT);
  }
  // ---- rank phase (no bases needed): 8 waves x 4 buckets each ----
  int blk = blockIdx.x;                            // 256 blocks per segment
  int seg = blk >> 8;
  int bk0 = (blk & 255) * 32 + wid * 4;
  u64 x0[4], x1[4]; int rr0[4], rr1[4], nn[4];
  #pragma unroll
  for (int k = 0; k < 4; ++k) {
    int B = seg * NBUCK + bk0 + k;
    u32 v = curs[B];
    int n = (int)(v > CAP ? CAP : v);
    nn[k] = n;
    const u64* src = srec + (size_t)B * CAP;
    u64 a0 = (lane < n) ? src[lane] : ~0ULL;
    u64 a1 = (lane + 64 < n) ? src[lane + 64] : ~0ULL;
    if (lane < n) buf[wid][lane] = a0;             // wave-private LDS, in-order DS
    if (lane + 64 < n) buf[wid][lane + 64] = a1;
    int r0 = 0, r1 = 0;
    for (int j = 0; j < n; ++j) {                  // broadcast reads, conflict-free
      u64 bj = buf[wid][j];
      r0 += (bj < a0);
      r1 += (bj < a1);
    }
    x0[k] = a0; x1[k] = a1; rr0[k] = r0; rr1[k] = r1;
  }
  // ---- wait for this segment's bases, then write ----
  if (tid == 0) {
    while (__hip_atomic_load(&flags[seg], __ATOMIC_RELAXED, __HIP_MEMORY_SCOPE_AGENT) == 0u)
      __builtin_amdgcn_s_sleep(16);
  }
  __syncthreads();
  (void)__hip_atomic_load(&flags[seg], __ATOMIC_ACQUIRE, __HIP_MEMORY_SCOPE_AGENT);
  const u32* bs = bases + seg * (NBUCK + 1);
  u32* aseg = a + (size_t)seg * NPTS;
  #pragma unroll
  for (int k = 0; k < 4; ++k) {
    int n = nn[k];
    u32 b0 = __hip_atomic_load(&bs[bk0 + k], __ATOMIC_RELAXED, __HIP_MEMORY_SCOPE_AGENT);
    u32* dst = aseg + b0;
    if (lane < n) dst[rr0[k]] = (u32)(x0[k] & 0x1FFFFULL);
    if (lane + 64 < n) dst[rr1[k]] = (u32)(x1[k] & 0x1FFFFULL);
  }
}

// ---- loss: exact replica bisect_left-on-unsorted + nearest; two interleaved chains per
// thread (R8-proven); fence-free fused final (validated R9/R10). ----
#define HALF (NSEG * NPTS / 2)                     // 125000
__global__ __launch_bounds__(256) void loss_kern(const u32* __restrict__ a_all,
                                                 u64* __restrict__ sums,
                                                 u32* __restrict__ tick,
                                                 const u32* __restrict__ oflow,
                                                 float* __restrict__ out,
                                                 int nblocks) {
  __shared__ u64 lsums[NSEG];
  __shared__ u32 rank_s;
  int tid = threadIdx.x;
  if (tid < NSEG) lsums[tid] = 0ULL;
  __syncthreads();
  int g = blockIdx.x * 256 + tid;
  if (g < HALF) {
    int g1 = g + HALF;
    int s0 = g / NPTS, s1 = g1 / NPTS;
    int vv0 = g - s0 * NPTS, vv1 = g1 - s1 * NPTS;
    const u32* A0 = a_all + (size_t)s0 * NPTS;
    const u32* A1 = a_all + (size_t)s1 * NPTS;
    int lo0 = 0, hi0 = NPTS, lo1 = 0, hi1 = NPTS;
    #pragma unroll
    for (int it = 0; it < NITER; ++it) {
      int mid0 = (lo0 + hi0) >> 1, mid1 = (lo1 + hi1) >> 1;
      int cm0 = mid0 > NPTS - 1 ? NPTS - 1 : mid0;
      int cm1 = mid1 > NPTS - 1 ? NPTS - 1 : mid1;
      int am0 = (int)A0[cm0];                      // two independent dependent-load chains
      int am1 = (int)A1[cm1];
      if (lo0 < hi0) { if (am0 < vv0) lo0 = mid0 + 1; else hi0 = mid0; }
      if (lo1 < hi1) { if (am1 < vv1) lo1 = mid1 + 1; else hi1 = mid1; }
    }
    {
      int pi = lo0 - 1; if (pi < 0) pi = 0; if (pi > NPTS - 1) pi = NPTS - 1;
      int ci = lo0;     if (ci > NPTS - 1) ci = NPTS - 1;
      int ap = (int)A0[pi], aa = (int)A0[ci];
      int d1 = vv0 - ap; if (d1 < 0) d1 = -d1;
      int d2 = vv0 - aa; if (d2 < 0) d2 = -d2;
      bool tp = (lo0 > 0) && ((lo0 == NPTS) || (d1 < d2));
      long long dd = (long long)(vv0 - (tp ? ap : aa));
      atomicAdd(&lsums[s0], (u64)(dd * dd));
    }
    {
      int pi = lo1 - 1; if (pi < 0) pi = 0; if (pi > NPTS - 1) pi = NPTS - 1;
      int ci = lo1;     if (ci > NPTS - 1) ci = NPTS - 1;
      int ap = (int)A1[pi], aa = (int)A1[ci];
      int d1 = vv1 - ap; if (d1 < 0) d1 = -d1;
      int d2 = vv1 - aa; if (d2 < 0) d2 = -d2;
      bool tp = (lo1 > 0) && ((lo1 == NPTS) || (d1 < d2));
      long long dd = (long long)(vv1 - (tp ? ap : aa));
      atomicAdd(&lsums[s1], (u64)(dd * dd));
    }
  }
  __syncthreads();
  if (tid < NSEG && lsums[tid]) atomicAdd(&sums[tid], lsums[tid]);
  __syncthreads();                                 // implies vmcnt(0): sums RMWs complete
  if (tid == 0) {
    rank_s = atomicAdd(&tick[1], 1u);
    if (rank_s == (u32)(nblocks - 1)) {            // fence-free fused final
      u32 of = __hip_atomic_load(oflow, __ATOMIC_RELAXED, __HIP_MEMORY_SCOPE_AGENT);
      if (of) { out[0] = 8.0e12f + 1.0e11f * (float)of; return; }
      double l = 0.0;
      for (int s = 0; s < NSEG; ++s) {
        u64 sv = __hip_atomic_load(&sums[s], __ATOMIC_RELAXED, __HIP_MEMORY_SCOPE_AGENT);
        l += (double)(long long)sv / (double)NPTS;
      }
      out[0] = (float)(l / 4.0);
    }
  }
}

__global__ void guard_kern(float* __restrict__ out) {
  if (threadIdx.x == 0 && blockIdx.x == 0) out[0] = 9.0e12f;
}

extern "C" void kernel_launch(void* const* d_in, const int* in_sizes, int n_in,
                              void* d_out, int out_size, void* d_ws, size_t ws_size,
                              hipStream_t stream) {
  (void)in_sizes; (void)n_in; (void)out_size;
  if (ws_size < WS_NEED) { guard_kern<<<1, 64, 0, stream>>>((float*)d_out); return; }
  const float* y   = (const float*)d_in[1];
  const float* rnd = (const float*)d_in[2];

  char* ws = (char*)d_ws;
  u64* srec   = (u64*)(ws + OFF_SREC);
  u32* aidx   = (u32*)(ws + OFF_A);
  u32* curs   = (u32*)(ws + OFF_CURS);
  u32* bases  = (u32*)(ws + OFF_BASES);
  u64* sums   = (u64*)(ws + OFF_SUMS);
  u32* tick   = (u32*)(ws + OFF_TICK);
  u32* oflow  = (u32*)(ws + OFF_OFLOW);
  u32* flags  = (u32*)(ws + OFF_FLAGS);
  float* out  = (float*)d_out;

  hipMemsetAsync(ws + OFF_CURS, 0, ZERO_BYTES, stream);   // curs..flags (graph memset node)
  conv_kern<<<dim3(16, 16, NSEG), dim3(16, 16), 0, stream>>>(y, rnd, srec, curs, oflow);
  bsortscan_kern<<<1024, 512, 0, stream>>>(srec, curs, bases, flags, tick, aidx, oflow);
  int nb = (HALF + 255) / 256;                     // 489
  loss_kern<<<nb, 256, 0, stream>>>(aidx, sums, tick, oflow, out, nb);
}

// Round 4
// 129.344 us; speedup vs baseline: 1.4833x; 1.4833x over previous
//
#include <hip/hip_runtime.h>
#include <stdint.h>

#define OH 250
#define OW 250
#define NPTS (OH*OW)        // 62500
#define NSEG 4              // y batches only (x-side is mathematically dead; verified R2-R10)
#define D 147               // 3*7*7
#define CH 3
#define IMH 256
#define IMW 256
#define NITER 17            // ceil(log2(62500)) + 1, per reference
#define NBUCK 8192
#define CAP 128             // slots/bucket; central lambda ~24, P(>128) ~ 0
#define SIG0 12.124355652982141  // sqrt(147): projection stddev model (bucketing only)

typedef unsigned long long u64;
typedef unsigned int u32;

// workspace layout (bytes)
#define OFF_SREC  0UL          // u64[4*8192*128] = 33,554,432
#define OFF_A     33554432UL   // u32[4*62500]    = 1,000,000
#define OFF_CURS  34559136UL   // u32[4*8192]     = 131,072
#define OFF_SUMS  34821296UL   // u64[4]          = 32
#define OFF_TICK  34821328UL   // u32[2]          = 8  (tick[1] = loss final ticket)
#define OFF_OFLOW 34821336UL   // u32[1]          = 4
#define WS_NEED   34821340UL
#define ZERO_BYTES (WS_NEED - OFF_CURS)            // 262,204: curs..oflow in one memset

__device__ __forceinline__ u64 packd(double f) {
  u64 u = (u64)__double_as_longlong(f);
  return (u & 0x8000000000000000ULL) ? ~u : (u | 0x8000000000000000ULL);
}

// bucket from the 47-bit-truncated transformed key (monotone with key order)
__device__ __forceinline__ int bucket_of(u64 rec) {
  u64 t = rec & ~0x1FFFFULL;
  u64 bits = (t & 0x8000000000000000ULL) ? (t & 0x7FFFFFFFFFFFFFFFULL) : ~t;
  double v = __longlong_as_double((long long)bits);
  double z = (v + 4.0 * SIG0) * ((double)NBUCK / (8.0 * SIG0));
  int b = (z <= 0.0) ? 0 : (int)z;
  if (b > NBUCK - 1) b = NBUCK - 1;
  return b;
}

// ---- conv (3x7x7, f64) + direct bucket scatter. setup fused (R13-validated): every
// block recomputes the 147 weights with the identical op sequence -> bit-identical f64
// -> identical records downstream. No cross-block communication anywhere. ----
__global__ __launch_bounds__(256) void conv_kern(const float* __restrict__ y,
                                                 const float* __restrict__ rnd,
                                                 u64* __restrict__ srec,
                                                 u32* __restrict__ curs,
                                                 u32* __restrict__ oflow) {
  __shared__ float tile[CH][22][22];
  __shared__ double wlds[D];
  int b = blockIdx.z;
  int tid = threadIdx.y * 16 + threadIdx.x;
  int lane = tid & 63;
  {  // weights: rand/std ddof=1 (same arithmetic as retired setup_kern, all waves replicate)
    const float* rb = rnd + b * D;
    double v0 = (double)rb[lane];
    double v1 = (double)rb[lane + 64];
    double v2 = (lane + 128 < D) ? (double)rb[lane + 128] : 0.0;
    double sm = v0 + v1 + v2;
    #pragma unroll
    for (int o = 32; o > 0; o >>= 1) sm += __shfl_xor(sm, o, 64);
    double mean = sm / (double)D;
    double d0 = v0 - mean, d1 = v1 - mean;
    double d2 = (lane + 128 < D) ? (v2 - mean) : 0.0;
    double ss = d0 * d0 + d1 * d1 + d2 * d2;
    #pragma unroll
    for (int o = 32; o > 0; o >>= 1) ss += __shfl_xor(ss, o, 64);
    double stdv = sqrt(ss / (double)(D - 1));
    if (tid < 64) {
      wlds[lane] = v0 / stdv;
      wlds[lane + 64] = v1 / stdv;
      if (lane + 128 < D) wlds[lane + 128] = v2 / stdv;
    }
  }
  const float* in = y + (size_t)b * CH * IMH * IMW;
  int bi = blockIdx.y * 16, bj = blockIdx.x * 16;
  for (int c = 0; c < CH; ++c)
    for (int t = tid; t < 22 * 22; t += 256) {
      int rr = t / 22, cc = t - rr * 22;
      int r = bi + rr, col = bj + cc;
      float v = 0.f;
      if (r < IMH && col < IMW) v = in[((size_t)c * IMH + r) * IMW + col];
      tile[c][rr][cc] = v;
    }
  __syncthreads();                                 // covers wlds + tile
  int i = bi + threadIdx.y, j = bj + threadIdx.x;
  if (i < OH && j < OW) {
    double acc = 0.0;
    #pragma unroll
    for (int c = 0; c < CH; ++c) {
      double ac = 0.0;                             // per-channel partial: 3 short chains
      #pragma unroll
      for (int ph = 0; ph < 7; ++ph)
        #pragma unroll
        for (int pw = 0; pw < 7; ++pw)
          ac = fma((double)tile[c][threadIdx.y + ph][threadIdx.x + pw],
                   wlds[c * 49 + ph * 7 + pw], ac);
      acc += ac;
    }
    int n = i * OW + j;
    u64 rec = (packd(acc) & ~0x1FFFFULL) | (u64)(u32)n;
    int bk = b * NBUCK + bucket_of(rec);
    u32 pos = atomicAdd(&curs[bk], 1u);
    if (pos < CAP) srec[(size_t)bk * CAP + pos] = rec;
    else atomicOr(oflow, 1u);                      // exactness tripwire (never expected)
  }
}

// ---- R14: bsort with REDUNDANT per-block scan (no cross-block sync — R11/R13 lesson).
// Each of 4096 blocks recomputes its segment's full exclusive scan of clamped counts
// into LDS (pure function of curs -> identical in every block -> deterministic), then
// 8 waves rank-sort one bucket each (R12-proven LDS broadcast loop) and write at the
// LDS bases offset. Deletes the scan node + boundary + bases global round-trip. ----
__global__ __launch_bounds__(512) void bsort_kern(const u64* __restrict__ srec,
                                                  const u32* __restrict__ curs,
                                                  u32* __restrict__ a,
                                                  u32* __restrict__ oflow) {
  __shared__ u32 bases_s[NBUCK];                   // 32 KB
  __shared__ u64 buf[8][CAP];                      // 8 KB
  __shared__ u32 wsum[8];
  int tid = threadIdx.x;
  int wid = tid >> 6, lane = tid & 63;
  int seg = blockIdx.x >> 10;                      // 1024 blocks per segment
  const u32* cs = curs + seg * NBUCK;
  // redundant scan: 512 thr x 16 counts, same sequential clamped order as old scan_kern
  u32 c[16]; u32 run = 0;
  #pragma unroll
  for (int m = 0; m < 16; ++m) {
    u32 v = cs[tid * 16 + m];
    c[m] = v > CAP ? CAP : v;                      // clamp: OOB-safety only
    run += c[m];
  }
  u32 inc = run;                                   // wave-inclusive scan
  #pragma unroll
  for (int o = 1; o < 64; o <<= 1) {
    u32 v = __shfl_up(inc, o, 64);
    if (lane >= o) inc += v;
  }
  if (lane == 63) wsum[wid] = inc;
  __syncthreads();
  u32 woff = 0;
  for (int w2 = 0; w2 < wid; ++w2) woff += wsum[w2];
  u32 ex = woff + inc - run;                       // block-exclusive prefix
  #pragma unroll
  for (int m = 0; m < 16; ++m) {
    bases_s[tid * 16 + m] = ex;
    ex += c[m];
  }
  if (tid == 511 && ex != NPTS) atomicOr(oflow, 2u);  // loud tripwire
  __syncthreads();
  // rank phase: one wave per bucket (R12-proven)
  int B = blockIdx.x * 8 + wid;                    // global bucket id, 32768 total
  int bk = B & (NBUCK - 1);
  u32 v = cs[bk];
  int n = (int)(v > CAP ? CAP : v);
  const u64* src = srec + (size_t)B * CAP;
  u32* dst = a + (size_t)seg * NPTS + bases_s[bk];
  for (int i = lane; i < n; i += 64) buf[wid][i] = src[i];
  __syncthreads();
  for (int i = lane; i < n; i += 64) {
    u64 x = buf[wid][i];
    int r = 0;
    for (int j = 0; j < n; ++j) r += (buf[wid][j] < x);   // LDS broadcast, conflict-free
    dst[r] = (u32)(x & 0x1FFFFULL);
  }
}

// ---- loss: exact replica bisect_left-on-unsorted + nearest; two interleaved chains per
// thread (R8-proven); fence-free fused final (validated R9/R10). ----
#define HALF (NSEG * NPTS / 2)                     // 125000
__global__ __launch_bounds__(256) void loss_kern(const u32* __restrict__ a_all,
                                                 u64* __restrict__ sums,
                                                 u32* __restrict__ tick,
                                                 const u32* __restrict__ oflow,
                                                 float* __restrict__ out,
                                                 int nblocks) {
  __shared__ u64 lsums[NSEG];
  __shared__ u32 rank_s;
  int tid = threadIdx.x;
  if (tid < NSEG) lsums[tid] = 0ULL;
  __syncthreads();
  int g = blockIdx.x * 256 + tid;
  if (g < HALF) {
    int g1 = g + HALF;
    int s0 = g / NPTS, s1 = g1 / NPTS;
    int vv0 = g - s0 * NPTS, vv1 = g1 - s1 * NPTS;
    const u32* A0 = a_all + (size_t)s0 * NPTS;
    const u32* A1 = a_all + (size_t)s1 * NPTS;
    int lo0 = 0, hi0 = NPTS, lo1 = 0, hi1 = NPTS;
    #pragma unroll
    for (int it = 0; it < NITER; ++it) {
      int mid0 = (lo0 + hi0) >> 1, mid1 = (lo1 + hi1) >> 1;
      int cm0 = mid0 > NPTS - 1 ? NPTS - 1 : mid0;
      int cm1 = mid1 > NPTS - 1 ? NPTS - 1 : mid1;
      int am0 = (int)A0[cm0];                      // two independent dependent-load chains
      int am1 = (int)A1[cm1];
      if (lo0 < hi0) { if (am0 < vv0) lo0 = mid0 + 1; else hi0 = mid0; }
      if (lo1 < hi1) { if (am1 < vv1) lo1 = mid1 + 1; else hi1 = mid1; }
    }
    {
      int pi = lo0 - 1; if (pi < 0) pi = 0; if (pi > NPTS - 1) pi = NPTS - 1;
      int ci = lo0;     if (ci > NPTS - 1) ci = NPTS - 1;
      int ap = (int)A0[pi], aa = (int)A0[ci];
      int d1 = vv0 - ap; if (d1 < 0) d1 = -d1;
      int d2 = vv0 - aa; if (d2 < 0) d2 = -d2;
      bool tp = (lo0 > 0) && ((lo0 == NPTS) || (d1 < d2));
      long long dd = (long long)(vv0 - (tp ? ap : aa));
      atomicAdd(&lsums[s0], (u64)(dd * dd));
    }
    {
      int pi = lo1 - 1; if (pi < 0) pi = 0; if (pi > NPTS - 1) pi = NPTS - 1;
      int ci = lo1;     if (ci > NPTS - 1) ci = NPTS - 1;
      int ap = (int)A1[pi], aa = (int)A1[ci];
      int d1 = vv1 - ap; if (d1 < 0) d1 = -d1;
      int d2 = vv1 - aa; if (d2 < 0) d2 = -d2;
      bool tp = (lo1 > 0) && ((lo1 == NPTS) || (d1 < d2));
      long long dd = (long long)(vv1 - (tp ? ap : aa));
      atomicAdd(&lsums[s1], (u64)(dd * dd));
    }
  }
  __syncthreads();
  if (tid < NSEG && lsums[tid]) atomicAdd(&sums[tid], lsums[tid]);
  __syncthreads();                                 // implies vmcnt(0): sums RMWs complete
  if (tid == 0) {
    rank_s = atomicAdd(&tick[1], 1u);
    if (rank_s == (u32)(nblocks - 1)) {            // fence-free fused final
      u32 of = __hip_atomic_load(oflow, __ATOMIC_RELAXED, __HIP_MEMORY_SCOPE_AGENT);
      if (of) { out[0] = 8.0e12f + 1.0e11f * (float)of; return; }
      double l = 0.0;
      for (int s = 0; s < NSEG; ++s) {
        u64 sv = __hip_atomic_load(&sums[s], __ATOMIC_RELAXED, __HIP_MEMORY_SCOPE_AGENT);
        l += (double)(long long)sv / (double)NPTS;
      }
      out[0] = (float)(l / 4.0);
    }
  }
}

__global__ void guard_kern(float* __restrict__ out) {
  if (threadIdx.x == 0 && blockIdx.x == 0) out[0] = 9.0e12f;
}

extern "C" void kernel_launch(void* const* d_in, const int* in_sizes, int n_in,
                              void* d_out, int out_size, void* d_ws, size_t ws_size,
                              hipStream_t stream) {
  (void)in_sizes; (void)n_in; (void)out_size;
  if (ws_size < WS_NEED) { guard_kern<<<1, 64, 0, stream>>>((float*)d_out); return; }
  const float* y   = (const float*)d_in[1];
  const float* rnd = (const float*)d_in[2];

  char* ws = (char*)d_ws;
  u64* srec   = (u64*)(ws + OFF_SREC);
  u32* aidx   = (u32*)(ws + OFF_A);
  u32* curs   = (u32*)(ws + OFF_CURS);
  u64* sums   = (u64*)(ws + OFF_SUMS);
  u32* tick   = (u32*)(ws + OFF_TICK);
  u32* oflow  = (u32*)(ws + OFF_OFLOW);
  float* out  = (float*)d_out;

  hipMemsetAsync(ws + OFF_CURS, 0, ZERO_BYTES, stream);   // curs..oflow (graph memset node)
  conv_kern<<<dim3(16, 16, NSEG), dim3(16, 16), 0, stream>>>(y, rnd, srec, curs, oflow);
  bsort_kern<<<NSEG * NBUCK / 8, 512, 0, stream>>>(srec, curs, aidx, oflow);
  int nb = (HALF + 255) / 256;                     // 489
  loss_kern<<<nb, 256, 0, stream>>>(aidx, sums, tick, oflow, out, nb);
}

// Round 5
// 123.794 us; speedup vs baseline: 1.5498x; 1.0448x over previous
//
#include <hip/hip_runtime.h>
#include <stdint.h>

#define OH 250
#define OW 250
#define NPTS (OH*OW)        // 62500
#define NSEG 4              // y batches only (x-side is mathematically dead; verified R2-R10)
#define D 147               // 3*7*7
#define CH 3
#define IMH 256
#define IMW 256
#define NITER 17            // ceil(log2(62500)) + 1, per reference
#define NBUCK 8192
#define CAP 128             // slots/bucket; central lambda ~24, P(>128) ~ 0
#define SIG0 12.124355652982141  // sqrt(147): projection stddev model (bucketing only)

typedef unsigned long long u64;
typedef unsigned int u32;

// workspace layout (bytes)
#define OFF_SREC  0UL          // u64[4*8192*128] = 33,554,432
#define OFF_A     33554432UL   // u32[4*62500]    = 1,000,000
#define OFF_WTS   34554432UL   // f64[4*147]      = 4,704
#define OFF_CURS  34559136UL   // u32[4*8192]     = 131,072
#define OFF_SUMS  34821296UL   // u64[4]          = 32
#define OFF_TICK  34821328UL   // u32[2]          = 8  (tick[1] = loss final ticket)
#define OFF_OFLOW 34821336UL   // u32[1]          = 4
#define WS_NEED   34821340UL

__device__ __forceinline__ u64 packd(double f) {
  u64 u = (u64)__double_as_longlong(f);
  return (u & 0x8000000000000000ULL) ? ~u : (u | 0x8000000000000000ULL);
}

// bucket from the 47-bit-truncated transformed key (monotone with key order)
__device__ __forceinline__ int bucket_of(u64 rec) {
  u64 t = rec & ~0x1FFFFULL;
  u64 bits = (t & 0x8000000000000000ULL) ? (t & 0x7FFFFFFFFFFFFFFFULL) : ~t;
  double v = __longlong_as_double((long long)bits);
  double z = (v + 4.0 * SIG0) * ((double)NBUCK / (8.0 * SIG0));
  int b = (z <= 0.0) ? 0 : (int)z;
  if (b > NBUCK - 1) b = NBUCK - 1;
  return b;
}

// ---- setup: blocks 0..3 weights (rand/std ddof=1, f64 -> global); blocks 4..35 zero ctrl
// (exact R12 form — best measured skeleton) ----
__global__ __launch_bounds__(256) void setup_kern(const float* __restrict__ rnd,
                                                  double* __restrict__ wts,
                                                  u32* __restrict__ curs,
                                                  u64* __restrict__ sums,
                                                  u32* __restrict__ tick,
                                                  u32* __restrict__ oflow) {
  int t = threadIdx.x;
  if (blockIdx.x < 4) {
    int b = blockIdx.x;
    int lane = t & 63;
    double v0 = (double)rnd[b * D + lane];
    double v1 = (double)rnd[b * D + lane + 64];
    double v2 = (lane + 128 < D) ? (double)rnd[b * D + lane + 128] : 0.0;
    double sm = v0 + v1 + v2;
    #pragma unroll
    for (int o = 32; o > 0; o >>= 1) sm += __shfl_xor(sm, o, 64);
    double mean = sm / (double)D;
    double d0 = v0 - mean, d1 = v1 - mean;
    double d2 = (lane + 128 < D) ? (v2 - mean) : 0.0;
    double ss = d0 * d0 + d1 * d1 + d2 * d2;
    #pragma unroll
    for (int o = 32; o > 0; o >>= 1) ss += __shfl_xor(ss, o, 64);
    double stdv = sqrt(ss / (double)(D - 1));
    if (t < 64) {                                  // one wave writes
      wts[b * D + lane] = v0 / stdv;
      wts[b * D + lane + 64] = v1 / stdv;
      if (lane + 128 < D) wts[b * D + lane + 128] = v2 / stdv;
    }
    if (b == 0 && t < 8) ((u32*)sums)[t] = 0u;
    if (b == 0 && t >= 8 && t < 10) tick[t - 8] = 0u;
    if (b == 0 && t == 10) oflow[0] = 0u;
  } else {
    int g = (blockIdx.x - 4) * 1024 + t * 4;       // 32 blocks cover 32768 u32
    if (g < NSEG * NBUCK) {
      curs[g] = 0u; curs[g + 1] = 0u; curs[g + 2] = 0u; curs[g + 3] = 0u;
    }
  }
}

// ---- conv (3x7x7, f64) + direct bucket scatter. Exact R12 form (LDS-staged weights). ----
__global__ __launch_bounds__(256) void conv_kern(const float* __restrict__ y,
                                                 const double* __restrict__ wts,
                                                 u64* __restrict__ srec,
                                                 u32* __restrict__ curs,
                                                 u32* __restrict__ oflow) {
  __shared__ float tile[CH][22][22];
  __shared__ double wlds[D];
  int b = blockIdx.z;
  const float* in = y + (size_t)b * CH * IMH * IMW;
  int bi = blockIdx.y * 16, bj = blockIdx.x * 16;
  int tid = threadIdx.y * 16 + threadIdx.x;
  if (tid < D) wlds[tid] = wts[b * D + tid];       // coalesced 147 x 8B, once per block
  for (int c = 0; c < CH; ++c)
    for (int t = tid; t < 22 * 22; t += 256) {
      int rr = t / 22, cc = t - rr * 22;
      int r = bi + rr, col = bj + cc;
      float v = 0.f;
      if (r < IMH && col < IMW) v = in[((size_t)c * IMH + r) * IMW + col];
      tile[c][rr][cc] = v;
    }
  __syncthreads();
  int i = bi + threadIdx.y, j = bj + threadIdx.x;
  if (i < OH && j < OW) {
    double acc = 0.0;
    #pragma unroll
    for (int c = 0; c < CH; ++c) {
      double ac = 0.0;                             // per-channel partial: 3 short chains
      #pragma unroll
      for (int ph = 0; ph < 7; ++ph)
        #pragma unroll
        for (int pw = 0; pw < 7; ++pw)
          ac = fma((double)tile[c][threadIdx.y + ph][threadIdx.x + pw],
                   wlds[c * 49 + ph * 7 + pw], ac);
      acc += ac;
    }
    int n = i * OW + j;
    u64 rec = (packd(acc) & ~0x1FFFFULL) | (u64)(u32)n;
    int bk = b * NBUCK + bucket_of(rec);
    u32 pos = atomicAdd(&curs[bk], 1u);
    if (pos < CAP) srec[(size_t)bk * CAP + pos] = rec;
    else atomicOr(oflow, 1u);                      // exactness tripwire (never expected)
  }
}

// ---- R15: fat-block bsort. 512 blocks x 512 thr (2 batches/CU — R14's 16-batch
// amplification lesson). Per-block redundant scan into LDS (R14-validated bit-exact;
// at 2 batches/CU costs ~2 us total, cheaper than the scan node it replaces). Each
// wave owns 8 buckets: all 16 record loads preloaded to registers (MLP), then
// wave-private LDS rank loop per bucket — no barriers between buckets (wave-internal
// DS ordering suffices; buf is wid-private). No cross-block sync anywhere. ----
__global__ __launch_bounds__(512) void bsort_kern(const u64* __restrict__ srec,
                                                  const u32* __restrict__ curs,
                                                  u32* __restrict__ a,
                                                  u32* __restrict__ oflow) {
  __shared__ u32 bases_s[NBUCK];                   // 32 KB
  __shared__ u64 buf[8][CAP];                      // 8 KB, wave-private rows
  __shared__ u32 wsum[8];
  int tid = threadIdx.x;
  int wid = tid >> 6, lane = tid & 63;
  int seg = blockIdx.x >> 7;                       // 128 blocks per segment
  const u32* cs = curs + seg * NBUCK;
  // redundant scan: 512 thr x 16 counts, same sequential clamped order as scan_kern
  {
    u32 c[16]; u32 run = 0;
    #pragma unroll
    for (int m = 0; m < 16; ++m) {
      u32 v = cs[tid * 16 + m];
      c[m] = v > CAP ? CAP : v;                    // clamp: OOB-safety only
      run += c[m];
    }
    u32 inc = run;                                 // wave-inclusive scan
    #pragma unroll
    for (int o = 1; o < 64; o <<= 1) {
      u32 v = __shfl_up(inc, o, 64);
      if (lane >= o) inc += v;
    }
    if (lane == 63) wsum[wid] = inc;
    __syncthreads();
    u32 woff = 0;
    for (int w2 = 0; w2 < wid; ++w2) woff += wsum[w2];
    u32 ex = woff + inc - run;                     // block-exclusive prefix
    #pragma unroll
    for (int m = 0; m < 16; ++m) {
      bases_s[tid * 16 + m] = ex;
      ex += c[m];
    }
    if (tid == 511 && ex != NPTS) atomicOr(oflow, 2u);  // loud tripwire
  }
  __syncthreads();
  // 8 buckets per wave; preload all records for cross-bucket MLP
  int bk0 = (blockIdx.x & 127) * 64 + wid * 8;
  u64 x0[8], x1[8]; int nn[8];
  #pragma unroll
  for (int k = 0; k < 8; ++k) {
    int bk = bk0 + k;
    u32 v = cs[bk];
    int n = (int)(v > CAP ? CAP : v);
    nn[k] = n;
    const u64* src = srec + (size_t)(seg * NBUCK + bk) * CAP;
    x0[k] = (lane < n) ? src[lane] : ~0ULL;
    x1[k] = (lane + 64 < n) ? src[lane + 64] : ~0ULL;
  }
  u32* aseg = a + (size_t)seg * NPTS;
  #pragma unroll
  for (int k = 0; k < 8; ++k) {
    int n = nn[k];
    if (n <= 0) continue;                          // wave-uniform
    if (lane < n) buf[wid][lane] = x0[k];          // wave-private, in-order DS
    if (lane + 64 < n) buf[wid][lane + 64] = x1[k];
    int r0 = 0, r1 = 0;
    for (int j = 0; j < n; ++j) {                  // LDS broadcast, conflict-free
      u64 bj = buf[wid][j];
      r0 += (bj < x0[k]);
      r1 += (bj < x1[k]);
    }
    u32* dst = aseg + bases_s[bk0 + k];
    if (lane < n) dst[r0] = (u32)(x0[k] & 0x1FFFFULL);
    if (lane + 64 < n) dst[r1] = (u32)(x1[k] & 0x1FFFFULL);
  }
}

// ---- loss: exact replica bisect_left-on-unsorted + nearest; two interleaved chains per
// thread (R8-proven); fence-free fused final (validated R9/R10). ----
#define HALF (NSEG * NPTS / 2)                     // 125000
__global__ __launch_bounds__(256) void loss_kern(const u32* __restrict__ a_all,
                                                 u64* __restrict__ sums,
                                                 u32* __restrict__ tick,
                                                 const u32* __restrict__ oflow,
                                                 float* __restrict__ out,
                                                 int nblocks) {
  __shared__ u64 lsums[NSEG];
  __shared__ u32 rank_s;
  int tid = threadIdx.x;
  if (tid < NSEG) lsums[tid] = 0ULL;
  __syncthreads();
  int g = blockIdx.x * 256 + tid;
  if (g < HALF) {
    int g1 = g + HALF;
    int s0 = g / NPTS, s1 = g1 / NPTS;
    int vv0 = g - s0 * NPTS, vv1 = g1 - s1 * NPTS;
    const u32* A0 = a_all + (size_t)s0 * NPTS;
    const u32* A1 = a_all + (size_t)s1 * NPTS;
    int lo0 = 0, hi0 = NPTS, lo1 = 0, hi1 = NPTS;
    #pragma unroll
    for (int it = 0; it < NITER; ++it) {
      int mid0 = (lo0 + hi0) >> 1, mid1 = (lo1 + hi1) >> 1;
      int cm0 = mid0 > NPTS - 1 ? NPTS - 1 : mid0;
      int cm1 = mid1 > NPTS - 1 ? NPTS - 1 : mid1;
      int am0 = (int)A0[cm0];                      // two independent dependent-load chains
      int am1 = (int)A1[cm1];
      if (lo0 < hi0) { if (am0 < vv0) lo0 = mid0 + 1; else hi0 = mid0; }
      if (lo1 < hi1) { if (am1 < vv1) lo1 = mid1 + 1; else hi1 = mid1; }
    }
    {
      int pi = lo0 - 1; if (pi < 0) pi = 0; if (pi > NPTS - 1) pi = NPTS - 1;
      int ci = lo0;     if (ci > NPTS - 1) ci = NPTS - 1;
      int ap = (int)A0[pi], aa = (int)A0[ci];
      int d1 = vv0 - ap; if (d1 < 0) d1 = -d1;
      int d2 = vv0 - aa; if (d2 < 0) d2 = -d2;
      bool tp = (lo0 > 0) && ((lo0 == NPTS) || (d1 < d2));
      long long dd = (long long)(vv0 - (tp ? ap : aa));
      atomicAdd(&lsums[s0], (u64)(dd * dd));
    }
    {
      int pi = lo1 - 1; if (pi < 0) pi = 0; if (pi > NPTS - 1) pi = NPTS - 1;
      int ci = lo1;     if (ci > NPTS - 1) ci = NPTS - 1;
      int ap = (int)A1[pi], aa = (int)A1[ci];
      int d1 = vv1 - ap; if (d1 < 0) d1 = -d1;
      int d2 = vv1 - aa; if (d2 < 0) d2 = -d2;
      bool tp = (lo1 > 0) && ((lo1 == NPTS) || (d1 < d2));
      long long dd = (long long)(vv1 - (tp ? ap : aa));
      atomicAdd(&lsums[s1], (u64)(dd * dd));
    }
  }
  __syncthreads();
  if (tid < NSEG && lsums[tid]) atomicAdd(&sums[tid], lsums[tid]);
  __syncthreads();                                 // implies vmcnt(0): sums RMWs complete
  if (tid == 0) {
    rank_s = atomicAdd(&tick[1], 1u);
    if (rank_s == (u32)(nblocks - 1)) {            // fence-free fused final
      u32 of = __hip_atomic_load(oflow, __ATOMIC_RELAXED, __HIP_MEMORY_SCOPE_AGENT);
      if (of) { out[0] = 8.0e12f + 1.0e11f * (float)of; return; }
      double l = 0.0;
      for (int s = 0; s < NSEG; ++s) {
        u64 sv = __hip_atomic_load(&sums[s], __ATOMIC_RELAXED, __HIP_MEMORY_SCOPE_AGENT);
        l += (double)(long long)sv / (double)NPTS;
      }
      out[0] = (float)(l / 4.0);
    }
  }
}

__global__ void guard_kern(float* __restrict__ out) {
  if (threadIdx.x == 0 && blockIdx.x == 0) out[0] = 9.0e12f;
}

extern "C" void kernel_launch(void* const* d_in, const int* in_sizes, int n_in,
                              void* d_out, int out_size, void* d_ws, size_t ws_size,
                              hipStream_t stream) {
  (void)in_sizes; (void)n_in; (void)out_size;
  if (ws_size < WS_NEED) { guard_kern<<<1, 64, 0, stream>>>((float*)d_out); return; }
  const float* y   = (const float*)d_in[1];
  const float* rnd = (const float*)d_in[2];

  char* ws = (char*)d_ws;
  u64* srec   = (u64*)(ws + OFF_SREC);
  u32* aidx   = (u32*)(ws + OFF_A);
  double* wts = (double*)(ws + OFF_WTS);
  u32* curs   = (u32*)(ws + OFF_CURS);
  u64* sums   = (u64*)(ws + OFF_SUMS);
  u32* tick   = (u32*)(ws + OFF_TICK);
  u32* oflow  = (u32*)(ws + OFF_OFLOW);
  float* out  = (float*)d_out;

  setup_kern<<<36, 256, 0, stream>>>(rnd, wts, curs, sums, tick, oflow);
  conv_kern<<<dim3(16, 16, NSEG), dim3(16, 16), 0, stream>>>(y, wts, srec, curs, oflow);
  bsort_kern<<<512, 512, 0, stream>>>(srec, curs, aidx, oflow);
  int nb = (HALF + 255) / 256;                     // 489
  loss_kern<<<nb, 256, 0, stream>>>(aidx, sums, tick, oflow, out, nb);
}